// Round 2
// baseline (146.477 us; speedup 1.0000x reference)
//
#include <hip/hip_runtime.h>
#include <cmath>

#define NCLS 81
#define ROW  (4 + NCLS)   // 85 floats per prior

__global__ __launch_bounds__(256) void ssd_decode_kernel(
    const float* __restrict__ inp,      // [N, 85]
    const float* __restrict__ priors,   // [N, 4]
    const float* __restrict__ var,      // [2]
    const float* __restrict__ thr,      // [1]
    float* __restrict__ out,            // [12*N] flat: boxes(4N) conf(N) pred(N) det(6N)
    int n)
{
    int i = blockIdx.x * 256 + threadIdx.x;
    if (i >= n) return;

    const float* row = inp + (long long)i * ROW;

    // loc
    float l0 = row[0], l1 = row[1], l2 = row[2], l3 = row[3];

    // logits -> registers (fully unrolled, static indices)
    float e[NCLS];
#pragma unroll
    for (int c = 0; c < NCLS; ++c) e[c] = row[4 + c];

    // row max (value only)
    float m = e[0];
#pragma unroll
    for (int c = 1; c < NCLS; ++c) m = fmaxf(m, e[c]);

    // correctly-rounded f32 exp: compute in double, round once to f32.
    // This mirrors np.exp(x - max) as closely as possible (incl. the
    // fl(1+x) behavior near 0 that creates argmax ties).
#pragma unroll
    for (int c = 0; c < NCLS; ++c) e[c] = (float)exp((double)(e[c] - m));

    // numpy pairwise_sum order for n=81: 8 accumulators, stride 8,
    // tree combine, then sequential tail (element 80).
    float r0=e[0], r1=e[1], r2=e[2], r3=e[3], r4=e[4], r5=e[5], r6=e[6], r7=e[7];
#pragma unroll
    for (int c = 8; c < 80; c += 8) {
        r0 += e[c+0]; r1 += e[c+1]; r2 += e[c+2]; r3 += e[c+3];
        r4 += e[c+4]; r5 += e[c+5]; r6 += e[c+6]; r7 += e[c+7];
    }
    float s = ((r0 + r1) + (r2 + r3)) + ((r4 + r5) + (r6 + r7));
    s += e[80];

    // softmax probs via true IEEE f32 division (matches np exactly given
    // the same e and s); argmax with first-occurrence tie-break OVER PROBS.
    float pm = -1.0f;
    int am = 0;
#pragma unroll
    for (int c = 0; c < NCLS; ++c) {
        float p = e[c] / s;
        if (p > pm) { pm = p; am = c; }
    }
    float conf = pm;   // == np.max(cls) — max of the rounded probs

    // decode box
    float4 pr = reinterpret_cast<const float4*>(priors)[i];
    float v0 = var[0], v1 = var[1];
    float cx = pr.x + l0 * v0 * pr.z;
    float cy = pr.y + l1 * v0 * pr.w;
    float w  = pr.z * expf(l2 * v1);
    float h  = pr.w * expf(l3 * v1);
    float x0 = cx - w * 0.5f;
    float y0 = cy - h * 0.5f;
    float x1 = x0 + w;
    float y1 = y0 + h;

    bool valid = (am > 0) && (conf > thr[0]);

    float4 box;
    box.x = valid ? x0 : 0.0f;
    box.y = valid ? y0 : 0.0f;
    box.z = valid ? x1 : 0.0f;
    box.w = valid ? y1 : 0.0f;
    float cz = valid ? conf : 0.0f;
    float pz = valid ? (float)(am - 1) : -1.0f;

    // boxes [N,4]
    reinterpret_cast<float4*>(out)[i] = box;
    // class_conf [N]
    out[(long long)4 * n + i] = cz;
    // class_pred [N] (as float; harness reads whole buffer as f32)
    out[(long long)5 * n + i] = pz;
    // detections [N,6] (8B-aligned: i*24 bytes)
    float* det = out + (long long)6 * n + (long long)i * 6;
    float2* det2 = reinterpret_cast<float2*>(det);
    det2[0] = make_float2(box.x, box.y);
    det2[1] = make_float2(box.z, box.w);
    det2[2] = make_float2(cz, pz);
}

extern "C" void kernel_launch(void* const* d_in, const int* in_sizes, int n_in,
                              void* d_out, int out_size, void* d_ws, size_t ws_size,
                              hipStream_t stream)
{
    const float* inp    = (const float*)d_in[0];
    const float* priors = (const float*)d_in[1];
    const float* var    = (const float*)d_in[2];
    const float* thr    = (const float*)d_in[3];
    float* out = (float*)d_out;

    int n = in_sizes[1] / 4;   // priors has N*4 elements
    int blocks = (n + 255) / 256;
    ssd_decode_kernel<<<blocks, 256, 0, stream>>>(inp, priors, var, thr, out, n);
}